// Round 7
// baseline (2548.716 us; speedup 1.0000x reference)
//
#include <hip/hip_runtime.h>
#include <hip/hip_bf16.h>

// LSTM: B=64, T=512, I=512, H=512. Output = final h [64,512] fp32.
//
// Round 7 = flag + untagged-payload sync (replaces tag-in-word).
//   Theory: round 6's residue = (a) poll vmcnt(0) folding in the xact
//   prefetch (~1us/step), (b) tag-in-word forces every poll round to
//   re-load the full 32KB payload per WG (~14 TB/s of MALL poll traffic
//   congesting the publishes).
//   Fix: producer stores h UNTAGGED bf16 (sc0sc1), per-wave vmcnt(0)
//   (= acked at coherence point), then one per-wave flag word = s+1.
//   Consumer polls 2 dwords/lane of flags (16x less traffic), then bulk
//   reads the payload ONCE: 4 x dwordx4/lane landing directly in MFMA
//   A-frag layout (no v_perm tag-strip, single-buffered LDS).
//   Flags monotone (poll with >=), zeroed in prep -> graph-replay safe.
//   xact prefetch pinned between payload asm and publish asm: >=800cy old
//   at every later vmcnt(0) -> no fold-in stalls.
//
//   Carried: xact = x@W_x via MFMA GEMM; 4 clusters x 32 WGs; wave v owns
//   hcols [16w+4v,+4) x all 4 gates (gate-major B-tile); XOR-butterfly gate
//   exchange; W_h register-resident (16 frags = 64 VGPR + asm anchors);
//   1 barrier/step.

#define T_STEPS 512
#define NBATCH  64
#define HID     512
#define NCL     4
#define WPC     32

typedef __attribute__((ext_vector_type(8))) short bf16x8;
typedef __attribute__((ext_vector_type(4))) float f32x4;
typedef __attribute__((ext_vector_type(4))) unsigned u32x4;

// ws layout (bytes)
#define WS_WHF  0                        // whfrag bf16, frag-order: 2MB
#define WS_WXT  (4u<<20)                 // wxT bf16 [2048][512]: 2MB
#define WS_HB   (8u<<20)                 // hbuf bf16 [2][64][512]: 128KB
#define WS_FLG  (WS_HB + (128u<<10))     // flags u32 [4][128 x stride4]: 8KB
#define WS_XBF  (16u<<20)                // xbf bf16 [32768][512]: 32MB
#define WS_XACT (48u<<20)                // xact bf16 [512][64][2048]: 128MB
#define WS_NEED ((size_t)(48u<<20) + ((size_t)T_STEPS*NBATCH*2048*2))

__device__ __forceinline__ short f2bf(float f) {
    unsigned u = __float_as_uint(f);
    unsigned r = u + 0x7fffu + ((u >> 16) & 1u);   // RNE
    return (short)(r >> 16);
}

// zero h_0 buffer (64KB) + flags (8KB): 72 blocks x 256 = 18432 words
__global__ void prep_zero(unsigned* hbuf0, unsigned* flags) {
    int gid = blockIdx.x * 256 + threadIdx.x;
    if (gid < 16384) hbuf0[gid] = 0u;
    else             flags[gid - 16384] = 0u;
}

__global__ void prep_xbf(const float* __restrict__ x, short* __restrict__ xbf) {
    size_t i8 = ((size_t)blockIdx.x * 256 + threadIdx.x) * 8;   // 8192 blocks
    f32x4 lo = *(const f32x4*)(x + i8);
    f32x4 hi = *(const f32x4*)(x + i8 + 4);
    bf16x8 v;
    v[0]=f2bf(lo[0]); v[1]=f2bf(lo[1]); v[2]=f2bf(lo[2]); v[3]=f2bf(lo[3]);
    v[4]=f2bf(hi[0]); v[5]=f2bf(hi[1]); v[6]=f2bf(hi[2]); v[7]=f2bf(hi[3]);
    *(bf16x8*)(xbf + i8) = v;
}

// wxT[n][k] = W_g[k][h], n = g*512+h, k in [0,512)  (x-part rows of W)
__global__ void prep_wx(const float* __restrict__ Wf, const float* __restrict__ Wi,
                        const float* __restrict__ Wo, const float* __restrict__ Wc,
                        short* __restrict__ wxT) {
    int gid = blockIdx.x * 256 + threadIdx.x;      // 512 blocks
    int n = gid >> 6, k0 = (gid & 63) * 8;
    int g = n >> 9, h = n & 511;
    const float* Wg = (g == 0) ? Wf : (g == 1) ? Wi : (g == 2) ? Wo : Wc;
    bf16x8 v;
#pragma unroll
    for (int e = 0; e < 8; ++e) v[e] = f2bf(Wg[(k0 + e) * 512 + h]);
    *(bf16x8*)(wxT + (size_t)n * 512 + k0) = v;
}

// whfrag, frag-order, GATE-MAJOR packed cols: B-tile col (l&15) = gate*4+hcl,
// hcol = 16w + 4v + hcl; value = W_gate[512 + kk*32 + (l>>4)*8 + e][hcol]
__global__ void prep_wh(const float* __restrict__ Wf, const float* __restrict__ Wi,
                        const float* __restrict__ Wo, const float* __restrict__ Wc,
                        short* __restrict__ whfrag) {
    int gid = blockIdx.x * 256 + threadIdx.x;      // 512 blocks: 32w*4v*16kk*64l
    int l = gid & 63, kk = (gid >> 6) & 15, v = (gid >> 10) & 3, w = gid >> 12;
    int c16 = l & 15, gate = c16 >> 2, hcl = c16 & 3;
    int hcol = 16 * w + 4 * v + hcl;
    const float* Wg = (gate == 0) ? Wf : (gate == 1) ? Wi : (gate == 2) ? Wo : Wc;
    int krow = 512 + kk * 32 + (l >> 4) * 8;
    bf16x8 vv;
#pragma unroll
    for (int e = 0; e < 8; ++e) vv[e] = f2bf(Wg[(krow + e) * 512 + hcol]);
    *(bf16x8*)(whfrag + (size_t)gid * 8) = vv;
}

// xact GEMM: [M=32768,K=512] x [K=512,N=2048] -> xact[t][b][n] bf16
__launch_bounds__(256, 1)
__global__ void xgemm(const short* __restrict__ xbf, const short* __restrict__ wxT,
                      short* __restrict__ xact) {
    const int l  = threadIdx.x & 63;
    const int wv = threadIdx.x >> 6;
    const int m0 = blockIdx.y * 128 + (wv >> 1) * 64;
    const int n0 = blockIdx.x * 128 + (wv & 1) * 64;

    f32x4 acc[4][4] = {};
    const short* ap = xbf + (size_t)(m0 + (l & 15)) * 512 + (l >> 4) * 8;
    const short* bp = wxT + (size_t)(n0 + (l & 15)) * 512 + (l >> 4) * 8;

    for (int kk = 0; kk < 16; ++kk) {
        bf16x8 a[4], b[4];
#pragma unroll
        for (int r = 0; r < 4; ++r) a[r] = *(const bf16x8*)(ap + r * 8192 + kk * 32);
#pragma unroll
        for (int q = 0; q < 4; ++q) b[q] = *(const bf16x8*)(bp + q * 8192 + kk * 32);
#pragma unroll
        for (int r = 0; r < 4; ++r)
#pragma unroll
            for (int q = 0; q < 4; ++q)
                acc[r][q] = __builtin_amdgcn_mfma_f32_16x16x32_bf16(a[r], b[q], acc[r][q], 0, 0, 0);
    }
#pragma unroll
    for (int r = 0; r < 4; ++r)
#pragma unroll
        for (int q = 0; q < 4; ++q)
#pragma unroll
            for (int j = 0; j < 4; ++j) {
                int m = m0 + r * 16 + (l >> 4) * 4 + j;
                int b_ = m >> 9, t = m & 511;
                int n = n0 + q * 16 + (l & 15);
                xact[((size_t)t * 64 + b_) * 2048 + n] = f2bf(acc[r][q][j]);
            }
}

__device__ __forceinline__ f32x4 shfx4(f32x4 v, int mask) {
    f32x4 r;
#pragma unroll
    for (int e = 0; e < 4; ++e) r[e] = __shfl_xor(v[e], mask, 64);
    return r;
}

// ---- recurrence -------------------------------------------------------------
__launch_bounds__(256, 1)
__global__ void lstm_rec(const short* __restrict__ xact,
                         const float* __restrict__ bfp, const float* __restrict__ bip,
                         const float* __restrict__ bop, const float* __restrict__ bcp,
                         const short* __restrict__ whfrag,
                         short* __restrict__ hbuf,        // [2][64][512] bf16
                         unsigned* __restrict__ flags,    // [4][128 x stride4]
                         float* __restrict__ out)         // [64][512] fp32
{
    const int tid = threadIdx.x;
    const int v   = tid >> 6;          // wave = hcol sub-slice (4 cols x 4 gates)
    const int l   = tid & 63;
    const int bid = blockIdx.x;
    const int cl  = bid & (NCL - 1);
    const int w   = bid >> 2;
    const int batch0 = cl * 16;

    // W_h fragments: 16 x bf16x8 = 64 VGPR, register-resident
    bf16x8 wfr[16];
    {
        const short* wp = whfrag + (((size_t)(w * 4 + v) * 16) * 64 + l) * 8;
#pragma unroll
        for (int kk = 0; kk < 16; ++kk)
            wfr[kk] = *(const bf16x8*)(wp + (size_t)kk * 512);
#pragma unroll
        for (int kk = 0; kk < 16; ++kk)
            asm volatile("" : "+v"(wfr[kk]));
    }

    const int g    = (l >> 2) & 3;              // this lane's gate
    const int hcol = 16 * w + 4 * v + (l & 3);  // this lane's h column
    const float* bp2 = (g == 0) ? bfp : (g == 1) ? bip : (g == 2) ? bop : bcp;
    const float bias = bp2[hcol];
    // unified activation: act = A*rcp(1+exp2(K*x)) + C
    const float Aa = (g == 3) ? 2.f : 1.f;
    const float Kk = (g == 3) ? -2.885390082f : -1.442695041f;
    const float Cc = (g == 3) ? -1.f : 0.f;

    __shared__ short alds[16][64][8];   // A-frags, single buffer (16KB)

    const int rowA  = batch0 + (l & 15);        // payload row (A-frag row = batch)
    const int rowD0 = batch0 + (l >> 4) * 4;    // D-frag row base (+j)
    const unsigned short* xa = (const unsigned short*)xact;

    unsigned*   flagp = flags + cl * 512 + (w * 4 + v) * 4;   // my flag word
    const char* fpl   = (const char*)(flags + cl * 512) + l * 16; // poll base

    f32x4 c = {0.f, 0.f, 0.f, 0.f};
    bool dead = false;

    // prefetch xact for s=0
    unsigned short xw[4], xwn[4];
#pragma unroll
    for (int j = 0; j < 4; ++j)
        xw[j] = xa[((size_t)0 * 64 + rowD0 + j) * 2048 + g * 512 + hcol];

    for (int s = 0; s < T_STEPS; ++s) {
        // ---- poll flags: all 128 producer-wave flags >= s (2 dwords/lane) ----
        {
            unsigned f0, f1;
            int spin = 0;
            while (true) {
                asm volatile(
                    "global_load_dword %0, %2, off sc0 sc1\n\t"
                    "global_load_dword %1, %2, off offset:1024 sc0 sc1\n\t"
                    "s_waitcnt vmcnt(0)"
                    : "=v"(f0), "=v"(f1) : "v"(fpl) : "memory");
                bool ok = (f0 >= (unsigned)s) & (f1 >= (unsigned)s);
                if (__all(ok) || dead) break;
                if (++spin > (1 << 17)) dead = true;
                else if (spin > 8) __builtin_amdgcn_s_sleep(1);
            }
        }

        // ---- payload: bulk-read K-quarter v of h_s, frag layout, once ----
        u32x4 p0, p1, p2, p3;
        {
            const char* hp = (const char*)(hbuf + (s & 1) * (NBATCH * HID)
                                           + rowA * HID)
                             + v * 256 + (l >> 4) * 16;
            asm volatile(
                "global_load_dwordx4 %0, %4, off sc0 sc1\n\t"
                "global_load_dwordx4 %1, %4, off offset:64 sc0 sc1\n\t"
                "global_load_dwordx4 %2, %4, off offset:128 sc0 sc1\n\t"
                "global_load_dwordx4 %3, %4, off offset:192 sc0 sc1\n\t"
                "s_waitcnt vmcnt(0)"
                : "=v"(p0), "=v"(p1), "=v"(p2), "=v"(p3)
                : "v"(hp) : "memory");
        }

        // ---- xact prefetch for s+1: pinned between the two asm fences ----
        if (s + 1 < T_STEPS) {
#pragma unroll
            for (int j = 0; j < 4; ++j)
                xwn[j] = xa[((size_t)(s + 1) * 64 + rowD0 + j) * 2048 + g * 512 + hcol];
        }

        // ---- ds_write own 4 frags (direct, no tag-strip) ----
        *(u32x4*)&alds[v * 4 + 0][l][0] = p0;
        *(u32x4*)&alds[v * 4 + 1][l][0] = p1;
        *(u32x4*)&alds[v * 4 + 2][l][0] = p2;
        *(u32x4*)&alds[v * 4 + 3][l][0] = p3;
        __syncthreads();   // single barrier per step

        // ---- 16 MFMA over K=512, 2 chains ----
        f32x4 acc0 = {0.f,0.f,0.f,0.f}, acc1 = {0.f,0.f,0.f,0.f};
#pragma unroll
        for (int kk = 0; kk < 16; kk += 2) {
            bf16x8 a0 = *(const bf16x8*)&alds[kk][l][0];
            bf16x8 a1 = *(const bf16x8*)&alds[kk + 1][l][0];
            acc0 = __builtin_amdgcn_mfma_f32_16x16x32_bf16(a0, wfr[kk],     acc0, 0, 0, 0);
            acc1 = __builtin_amdgcn_mfma_f32_16x16x32_bf16(a1, wfr[kk + 1], acc1, 0, 0, 0);
        }
        f32x4 pre = acc0 + acc1;

        // ---- unified activation (this lane's gate, 4 rows) ----
        f32x4 own;
#pragma unroll
        for (int j = 0; j < 4; ++j) {
            float vv = pre[j] + __uint_as_float((unsigned)xw[j] << 16) + bias;
            float e  = __builtin_amdgcn_exp2f(Kk * vv);
            own[j]   = __builtin_fmaf(Aa, __builtin_amdgcn_rcpf(1.f + e), Cc);
        }
#pragma unroll
        for (int j = 0; j < 4; ++j) xw[j] = xwn[j];

        // ---- in-wave XOR butterfly: gather f,i,o,C (lanes l^4, l^8) ----
        f32x4 r1 = shfx4(own, 4);
        f32x4 r2 = shfx4(own, 8);
        f32x4 r3 = shfx4(r1, 8);
        f32x4 fv = (g == 0) ? own : (g == 1) ? r1 : (g == 2) ? r2 : r3;
        f32x4 iv = (g == 0) ? r1 : (g == 1) ? own : (g == 2) ? r3 : r2;
        f32x4 ov = (g == 0) ? r2 : (g == 1) ? r3 : (g == 2) ? own : r1;
        f32x4 Cv = (g == 0) ? r3 : (g == 1) ? r2 : (g == 2) ? r1 : own;

        // ---- c update (4x lane-redundant, deterministic) ----
        c = fv * c + iv * Cv;

        // ---- publish: this lane stores row rowD0+g (its gate id) ----
        float cg  = (g == 0) ? c[0] : (g == 1) ? c[1] : (g == 2) ? c[2] : c[3];
        float og  = (g == 0) ? ov[0] : (g == 1) ? ov[1] : (g == 2) ? ov[2] : ov[3];
        float e2  = __builtin_amdgcn_exp2f(-2.885390082f * cg);
        float th  = __builtin_fmaf(2.f, __builtin_amdgcn_rcpf(1.f + e2), -1.f);
        float h   = og * th;
        int   row = rowD0 + g;
        if (s == T_STEPS - 1) {
            out[row * HID + hcol] = h;
        } else {
            short* hd = hbuf + ((s + 1) & 1) * (NBATCH * HID) + row * HID + hcol;
            unsigned hv = (unsigned)(unsigned short)f2bf(h);
            asm volatile("global_store_short %0, %1, off sc0 sc1"
                         :: "v"(hd), "v"(hv) : "memory");
            // drain h stores to the coherence point, then announce
            asm volatile("s_waitcnt vmcnt(0)" ::: "memory");
            __hip_atomic_store(flagp, (unsigned)(s + 1),
                               __ATOMIC_RELAXED, __HIP_MEMORY_SCOPE_AGENT);
        }
    }
}

extern "C" void kernel_launch(void* const* d_in, const int* in_sizes, int n_in,
                              void* d_out, int out_size, void* d_ws, size_t ws_size,
                              hipStream_t stream) {
    const float* x  = (const float*)d_in[0];
    const float* Wf = (const float*)d_in[1];
    const float* bf = (const float*)d_in[2];
    const float* Wi = (const float*)d_in[3];
    const float* bi = (const float*)d_in[4];
    const float* Wo = (const float*)d_in[5];
    const float* bo = (const float*)d_in[6];
    const float* Wc = (const float*)d_in[7];
    const float* bc = (const float*)d_in[8];

    if (ws_size < WS_NEED) return;   // loud failure: out stays poison

    char*     ws     = (char*)d_ws;
    short*    whfrag = (short*)(ws + WS_WHF);
    short*    wxT    = (short*)(ws + WS_WXT);
    short*    hbuf   = (short*)(ws + WS_HB);
    unsigned* flags  = (unsigned*)(ws + WS_FLG);
    short*    xbf    = (short*)(ws + WS_XBF);
    short*    xact   = (short*)(ws + WS_XACT);

    prep_zero<<<dim3(72),   dim3(256), 0, stream>>>((unsigned*)hbuf, flags);
    prep_xbf <<<dim3(8192), dim3(256), 0, stream>>>(x, xbf);
    prep_wx  <<<dim3(512),  dim3(256), 0, stream>>>(Wf, Wi, Wo, Wc, wxT);
    prep_wh  <<<dim3(512),  dim3(256), 0, stream>>>(Wf, Wi, Wo, Wc, whfrag);
    xgemm    <<<dim3(16, 256), dim3(256), 0, stream>>>(xbf, wxT, xact);
    lstm_rec <<<dim3(NCL * WPC), dim3(256), 0, stream>>>(
        xact, bf, bi, bo, bc, whfrag, hbuf, flags, (float*)d_out);
}